// Round 1
// baseline (2914.706 us; speedup 1.0000x reference)
//
#include <hip/hip_runtime.h>

// AbstractConv3D: 16 levels of dense R^3 grids, per-level 3x3x3 conv,
// C_in = C_out = 16, B = 2, fp32, SAME (zero) padding.
// Round 1: fp32 VALU baseline. Each block = 1024 consecutive voxels of one
// level; each thread computes 4 voxels x 16 c_out. Weights (27*16*16 floats)
// staged in LDS, read as wave-uniform float4 broadcasts (conflict-free);
// 4 voxels/thread amortizes the LDS reads 4x over the FMAs -> FMA-bound.

#define NLEV 16
#define NTOT 1844282   // sum of R^3 over levels

// Static tables (RESOLUTIONS is a compile-time constant in the reference).
__constant__ int c_res[NLEV]  = {16,18,20,22,24,27,30,34,38,42,47,52,58,64,72,80};
__constant__ int c_voff[NLEV] = {0,4096,9928,17928,28576,42400,62083,89083,
                                 128387,183259,257347,361170,501778,696890,
                                 959034,1332282};
// block offsets with 1024 voxels/block: cumsum(ceil(R^3/1024))
__constant__ int c_blk[NLEV+1] = {0,4,10,18,29,43,63,90,129,183,256,358,496,
                                  687,943,1308,1808};

__global__ __launch_bounds__(256)
void conv3d_fp32_kernel(const float* __restrict__ in,
                        const float* __restrict__ w,
                        const float* __restrict__ bias,
                        float* __restrict__ out) {
    __shared__ __align__(16) float s_w[27 * 256];
    __shared__ float s_b[16];

    const int bid = blockIdx.x;
    const int b   = blockIdx.y;

    // level lookup (wave-uniform, 15 scalar compares against constant mem)
    int l = 0;
#pragma unroll
    for (int i = 1; i < NLEV; ++i) l += (bid >= c_blk[i]);

    const int R    = c_res[l];
    const int voff = c_voff[l];
    const int R3   = R * R * R;

    // stage this level's weights + bias into LDS
    {
        const float* wg = w + l * 27 * 256;
        for (int t = threadIdx.x; t < 27 * 256; t += 256) s_w[t] = wg[t];
        if (threadIdx.x < 16) s_b[threadIdx.x] = bias[l * 16 + threadIdx.x];
    }
    __syncthreads();

    const int i0 = (bid - c_blk[l]) * 1024 + threadIdx.x * 4;
    if (i0 >= R3) return;

    const float* inb  = in  + ((long long)b * NTOT + voff) * 16;
    float*       outb = out + ((long long)b * NTOT + voff) * 16;

    // decode 4 voxels (row-major x,y,z)
    int X[4], Y[4], Z[4];
    bool valid[4];
#pragma unroll
    for (int v = 0; v < 4; ++v) {
        const int i = i0 + v;
        valid[v] = (i < R3);
        const int ii = valid[v] ? i : 0;
        Z[v] = ii % R;
        const int t = ii / R;
        Y[v] = t % R;
        X[v] = t / R;
    }

    float acc[4][16];
#pragma unroll
    for (int v = 0; v < 4; ++v)
#pragma unroll
        for (int co = 0; co < 16; ++co) acc[v][co] = s_b[co];

    // tap loops kept rolled: body ~1.2K instructions stays I-cache resident
#pragma unroll 1
    for (int kd = 0; kd < 3; ++kd) {
#pragma unroll 1
        for (int kh = 0; kh < 3; ++kh) {
#pragma unroll 1
            for (int kw = 0; kw < 3; ++kw) {
                const int tap = (kd * 3 + kh) * 3 + kw;
                const float4* wt = reinterpret_cast<const float4*>(&s_w[tap * 256]);

                // gather 4 voxels' neighbor input vectors (zero-padded)
                float iv[4][16];
#pragma unroll
                for (int v = 0; v < 4; ++v) {
                    const int nx = X[v] + kd - 1;
                    const int ny = Y[v] + kh - 1;
                    const int nz = Z[v] + kw - 1;
                    const bool ok = valid[v] & (nx >= 0) & (nx < R) &
                                    (ny >= 0) & (ny < R) & (nz >= 0) & (nz < R);
                    const int nidx = ok ? ((nx * R + ny) * R + nz) * 16 : 0;
                    const float4* ip = reinterpret_cast<const float4*>(inb + nidx);
#pragma unroll
                    for (int g = 0; g < 4; ++g) {
                        float4 q = ip[g];
                        if (!ok) { q.x = 0.f; q.y = 0.f; q.z = 0.f; q.w = 0.f; }
                        iv[v][g * 4 + 0] = q.x;
                        iv[v][g * 4 + 1] = q.y;
                        iv[v][g * 4 + 2] = q.z;
                        iv[v][g * 4 + 3] = q.w;
                    }
                }

                // 16 ci x 16 co x 4 voxels FMAs; weights are wave-uniform
                // LDS broadcasts (no bank conflicts)
#pragma unroll
                for (int ci = 0; ci < 16; ++ci) {
                    const float4 w0 = wt[ci * 4 + 0];
                    const float4 w1 = wt[ci * 4 + 1];
                    const float4 w2 = wt[ci * 4 + 2];
                    const float4 w3 = wt[ci * 4 + 3];
                    float wv[16] = {w0.x, w0.y, w0.z, w0.w,
                                    w1.x, w1.y, w1.z, w1.w,
                                    w2.x, w2.y, w2.z, w2.w,
                                    w3.x, w3.y, w3.z, w3.w};
#pragma unroll
                    for (int v = 0; v < 4; ++v) {
                        const float a = iv[v][ci];
#pragma unroll
                        for (int co = 0; co < 16; ++co)
                            acc[v][co] = fmaf(a, wv[co], acc[v][co]);
                    }
                }
            }
        }
    }

    // write 4 voxels x 16 c_out as float4s
#pragma unroll
    for (int v = 0; v < 4; ++v) {
        if (!valid[v]) continue;
        float4* op = reinterpret_cast<float4*>(outb + (i0 + v) * 16);
#pragma unroll
        for (int g = 0; g < 4; ++g) {
            float4 q;
            q.x = acc[v][g * 4 + 0];
            q.y = acc[v][g * 4 + 1];
            q.z = acc[v][g * 4 + 2];
            q.w = acc[v][g * 4 + 3];
            op[g] = q;
        }
    }
}

extern "C" void kernel_launch(void* const* d_in, const int* in_sizes, int n_in,
                              void* d_out, int out_size, void* d_ws, size_t ws_size,
                              hipStream_t stream) {
    const float* in   = (const float*)d_in[0];   // (B, N, 16) fp32
    const float* w    = (const float*)d_in[1];   // (16, 3,3,3, 16, 16) fp32
    const float* bias = (const float*)d_in[2];   // (16, 16) fp32
    // d_in[3] offsets / d_in[4] resolutions are static; baked into tables.
    float* out = (float*)d_out;                  // (B, N, 16) fp32

    dim3 grid(1808, 2);
    conv3d_fp32_kernel<<<grid, 256, 0, stream>>>(in, w, bias, out);
}

// Round 2
// 488.006 us; speedup vs baseline: 5.9727x; 5.9727x over previous
//
#include <hip/hip_runtime.h>

// AbstractConv3D: 16 dense R^3 levels, 3x3x3 conv, C_in=C_out=16, B=2, fp32 I/O.
// Round 2: LDS-tiled bf16 MFMA.
//   block = (4x,4y,16z) tile of one level; halo 6x6x18 staged to LDS as bf16,
//   voxel stride 48 B (16 ci * 2 B + 16 B pad -> conflict-free b128 access).
//   Each wave (4/block) owns one x-slice (dx = wave id), computes 4 z-runs
//   (dy = 0..3) of 16 voxels via 14x mfma_f32_16x16x32_bf16 (K = 2 taps x 16 ci;
//   28th tap zero-weighted, A-addr clamped to tap 26 so 0*junk can't be NaN).
//   A-frag: one ds_read_b128/lane (per-lane tap geometry -> 14 precomputed offsets).
//   B-frag: 56 VGPRs of weights built once per wave from global (L2-resident).
//   D: col=lane&15=c_out, row=quad*4+reg=z (verified layout). acc init = bias.

#define NLEV 16
#define NTOT 1844282

typedef short  short8 __attribute__((ext_vector_type(8)));
typedef float  f32x4  __attribute__((ext_vector_type(4)));

__constant__ int c_res[NLEV]  = {16,18,20,22,24,27,30,34,38,42,47,52,58,64,72,80};
__constant__ int c_voff[NLEV] = {0,4096,9928,17928,28576,42400,62083,89083,
                                 128387,183259,257347,361170,501778,696890,
                                 959034,1332282};
// tiles per level: ceil(R/4)^2 * ceil(R/16), cumulative
__constant__ int c_tblk[NLEV+1] = {0,16,66,116,188,260,358,486,729,1029,1392,
                                   1824,2500,3400,4424,6044,8044};
__constant__ int c_ntz[NLEV] = {1,2,2,2,2,2,2,3,3,3,3,4,4,4,5,5};
__constant__ int c_nty[NLEV] = {4,5,5,6,6,7,8,9,10,11,12,13,15,16,18,20};

__device__ __forceinline__ unsigned short f2bf(float f) {
    union { float f; unsigned int u; } v; v.f = f;
    unsigned int u = v.u;
    return (unsigned short)((u + 0x7FFFu + ((u >> 16) & 1u)) >> 16);
}

__device__ __forceinline__ short8 lds_load8(const short* p) {
    return *reinterpret_cast<const short8*>(__builtin_assume_aligned(p, 16));
}
__device__ __forceinline__ void lds_store8(short* p, short8 v) {
    *reinterpret_cast<short8*>(__builtin_assume_aligned(p, 16)) = v;
}

__global__ __launch_bounds__(256, 3)
void conv3d_mfma_kernel(const float* __restrict__ in,
                        const float* __restrict__ w,
                        const float* __restrict__ bias,
                        float* __restrict__ out) {
    // 648 halo voxels * 24 shorts (16 data + 8 pad) = 31104 B
    __shared__ __align__(16) short s_in[648 * 24];

    const int bid = blockIdx.x;
    const int b   = blockIdx.y;

    int l = 0;
#pragma unroll
    for (int i = 1; i < NLEV; ++i) l += (bid >= c_tblk[i]);

    const int R    = c_res[l];
    const int voff = c_voff[l];
    const int ntz  = c_ntz[l];
    const int nty  = c_nty[l];

    const int local = bid - c_tblk[l];
    const int tz = local % ntz;
    const int t2 = local / ntz;
    const int ty = t2 % nty;
    const int tx = t2 / nty;

    const float* inb  = in  + ((long long)b * NTOT + voff) * 16;
    float*       outb = out + ((long long)b * NTOT + voff) * 16;

    // ---- stage halo tile (6 x 6 x 18) into LDS as bf16, zeros outside grid ----
    for (int h = threadIdx.x; h < 648; h += 256) {
        const int hz = h % 18;
        const int t  = h / 18;
        const int hy = t % 6;
        const int hx = t / 6;
        const int gx = tx * 4 - 1 + hx;
        const int gy = ty * 4 - 1 + hy;
        const int gz = tz * 16 - 1 + hz;
        const bool ok = ((unsigned)gx < (unsigned)R) &
                        ((unsigned)gy < (unsigned)R) &
                        ((unsigned)gz < (unsigned)R);
        short v[16];
        if (ok) {
            const float4* ip = reinterpret_cast<const float4*>(
                inb + (long long)((gx * R + gy) * R + gz) * 16);
#pragma unroll
            for (int g = 0; g < 4; ++g) {
                float4 q = ip[g];
                v[g * 4 + 0] = (short)f2bf(q.x);
                v[g * 4 + 1] = (short)f2bf(q.y);
                v[g * 4 + 2] = (short)f2bf(q.z);
                v[g * 4 + 3] = (short)f2bf(q.w);
            }
        } else {
#pragma unroll
            for (int g = 0; g < 16; ++g) v[g] = 0;
        }
        short8 lo, hi;
#pragma unroll
        for (int g = 0; g < 8; ++g) { lo[g] = v[g]; hi[g] = v[8 + g]; }
        lds_store8(&s_in[h * 24], lo);
        lds_store8(&s_in[h * 24 + 8], hi);
    }

    // ---- per-lane MFMA geometry + weight fragments (overlaps staging) ----
    const int lane = threadIdx.x & 63;
    const int wv   = threadIdx.x >> 6;     // wave id = dx (x within tile)
    const int quad = lane >> 4;
    const int m    = lane & 15;            // A-row (z) / D-col (c_out)
    const int co   = m;
    const int h8   = (quad & 1) * 8;       // ci half
    const int qh   = quad >> 1;            // tap parity within K=32

    const float* wlev = w + l * 6912;      // 27*16*16
    const float  bv   = bias[l * 16 + co];

    int    ofs[14];
    short8 wf[14];
#pragma unroll
    for (int i = 0; i < 14; ++i) {
        const int t  = 2 * i + qh;         // tap 0..27
        const int ta = t > 26 ? 26 : t;    // clamp padded tap's A-address
        const int kd = ta / 9;
        const int rr = ta - kd * 9;
        const int kh = rr / 3;
        const int kw = rr - kh * 3;
        ofs[i] = ((kd * 6 + kh) * 18 + kw + m) * 24 + h8;
        short8 wv8;
        if (t < 27) {
            const float* wp = wlev + t * 256 + h8 * 16 + co;
#pragma unroll
            for (int j = 0; j < 8; ++j) wv8[j] = (short)f2bf(wp[j * 16]);
        } else {
#pragma unroll
            for (int j = 0; j < 8; ++j) wv8[j] = 0;
        }
        wf[i] = wv8;
    }

    __syncthreads();

    // ---- compute: wave = x-slice dx=wv; 4 z-runs (dy=0..3) of 16 voxels ----
    const int gx = tx * 4 + wv;
    if (gx < R) {
        const int pb0 = wv * 2592;          // (dx*6)*18*24
#pragma unroll
        for (int j = 0; j < 4; ++j) {
            const int gy = ty * 4 + j;
            if (gy < R) {
                f32x4 acc = {bv, bv, bv, bv};
                const int pb = pb0 + j * 432;   // + dy*18*24
#pragma unroll
                for (int i = 0; i < 14; ++i) {
                    short8 a = lds_load8(&s_in[pb + ofs[i]]);
                    acc = __builtin_amdgcn_mfma_f32_16x16x32_bf16(a, wf[i], acc, 0, 0, 0);
                }
                float* ob = outb + (long long)(gx * R + gy) * R * 16 + co;
                const int gz0 = tz * 16 + quad * 4;
#pragma unroll
                for (int r = 0; r < 4; ++r) {
                    const int gz = gz0 + r;
                    if (gz < R) ob[(long long)gz * 16] = acc[r];
                }
            }
        }
    }
}

extern "C" void kernel_launch(void* const* d_in, const int* in_sizes, int n_in,
                              void* d_out, int out_size, void* d_ws, size_t ws_size,
                              hipStream_t stream) {
    const float* in   = (const float*)d_in[0];   // (B, N, 16) fp32
    const float* w    = (const float*)d_in[1];   // (16, 3,3,3, 16, 16) fp32
    const float* bias = (const float*)d_in[2];   // (16, 16) fp32
    float* out = (float*)d_out;                  // (B, N, 16) fp32

    dim3 grid(8044, 2);
    conv3d_mfma_kernel<<<grid, 256, 0, stream>>>(in, w, bias, out);
}